// Round 15
// baseline (124.811 us; speedup 1.0000x reference)
//
#include <hip/hip_runtime.h>
#include <hip/hip_bf16.h>

typedef short short8 __attribute__((ext_vector_type(8)));
typedef float f32x4 __attribute__((ext_vector_type(4)));
typedef unsigned int uint;

#define CB   16
#define TT   8
#define CIN  1024
#define ICH  512
#define HWS  196
#define NPB  1568   // cols per batch (196*8)
#define NF   25088  // flat cols = 16*1568

static __device__ __forceinline__ unsigned short f2bf(float f) {
  __hip_bfloat16 h = __float2bfloat16(f); unsigned short u; __builtin_memcpy(&u, &h, 2); return u;
}

// async global->LDS, 16B per lane; LDS dest is wave-uniform base + lane*16
static __device__ __forceinline__ void stage16(const void* g, void* l) {
  __builtin_amdgcn_global_load_lds(
      (const __attribute__((address_space(1))) unsigned int*)(unsigned long long)g,
      (__attribute__((address_space(3))) unsigned int*)(unsigned int)(unsigned long long)l,
      16, 0, 0);
}

// ---------------- weight prep (unchanged) ----------------
__global__ void k_prep_w(const float* __restrict__ w1, const float* __restrict__ w2,
    const float* __restrict__ wb1, const float* __restrict__ bb1,
    const float* __restrict__ wb2, const float* __restrict__ bb2,
    const float* __restrict__ wb3, const float* __restrict__ bb3,
    const float* __restrict__ wb4, const float* __restrict__ bb4,
    __hip_bfloat16* __restrict__ w1b, __hip_bfloat16* __restrict__ w2b,
    float* __restrict__ weff, float* __restrict__ beff) {
  int idx = blockIdx.x * 256 + threadIdx.x;
  if (idx < CIN * ICH) {
    w1b[idx] = __float2bfloat16(w1[idx]);
    w2b[idx] = __float2bfloat16(w2[idx]);
  }
  if (idx < ICH) {
    float e[7];
#pragma unroll
    for (int u = 0; u < 7; u++) e[u] = wb4[idx * 7 + u];
#pragma unroll
    for (int u = 0; u < 5; u++) e[u + 1] += wb3[idx * 5 + u];
#pragma unroll
    for (int u = 0; u < 3; u++) e[u + 2] += wb2[idx * 3 + u];
    e[3] += wb1[idx];
#pragma unroll
    for (int u = 0; u < 7; u++) weff[idx * 8 + u] = e[u];
    weff[idx * 8 + 7] = 0.f;
    beff[idx] = bb1[idx] + bb2[idx] + bb3[idx] + bb4[idx];
  }
}

// ---------------- x transpose v3 (unchanged, R14-proven) ----------------
__global__ __launch_bounds__(448) void k_prep_x(const float* __restrict__ x,
                                                __hip_bfloat16* __restrict__ xbT) {
  __shared__ unsigned short tile[196 * 128];  // 50176 B
  int xcd = blockIdx.x & 7, i = blockIdx.x >> 3;
  int id = xcd * 128 + i;
  int bt = id >> 3, cr = id & 7;
  int c0 = cr * 128;
  int b = bt >> 3, t = bt & 7;
  const float* src = x + ((size_t)bt * CIN + c0) * HWS;
  int tid = threadIdx.x;
#pragma unroll
  for (int it = 0; it < 14; it++) {
    int idx = it * 448 + tid;               // = c*49 + hwq
    f32x4 v = *(const f32x4*)(src + (size_t)idx * 4);
    int c = idx / 49, hwq = idx - c * 49;
#pragma unroll
    for (int j = 0; j < 4; j++) {
      int hw = hwq * 4 + j;
      int slot = (c >> 3) ^ ((hw + (hw >> 2)) & 15);
      tile[hw * 128 + slot * 8 + (c & 7)] = f2bf(v[j]);
    }
  }
  __syncthreads();
  __hip_bfloat16* dstb = xbT + ((size_t)b * NPB + (size_t)t) * CIN + c0;
#pragma unroll
  for (int it = 0; it < 7; it++) {
    int idx = it * 448 + tid;               // = hw*16 + co
    int hw = idx >> 4, co = idx & 15;
    int slot = co ^ ((hw + (hw >> 2)) & 15);
    uint4 val = *(const uint4*)&tile[hw * 128 + slot * 8];
    *(uint4*)(dstb + (size_t)(hw * 8) * CIN + co * 8) = val;
  }
}

// ---------------- 256x128 GEMM core, BK=32, 8 waves (4m x 2n), 2 blocks/CU ----------------
// A 256 rows (m-like), B 128 rows (n-like); per-wave 64x64, acc[4][4] (64 VGPR).
// LDS: 2 bufs x (A 16KB + B 8KB) = 48 KB -> 2-3 blocks/CU (cross-block latency cover).
// Staging per tile per thread: 3 stage16 (A h0, A h1, B). Counted vmcnt(3): stage(t+1)
// issued before the wait, which drains only tile t (issued one iter earlier).
// Swizzle (64-B rows, 4 chunks of 16B): LDS slot s of row r holds global chunk
// s ^ perm(r), perm(r) = (r&3) ^ ((r>>2)&3). Plain r&3 would 4-way-conflict: with
// 64-B rows, bank = (row&1)*16 + slot*4 + sub, and b128 lanes sharing (ln&3) sit 4
// rows apart (same parity) -> same bank. The extra (r>>2) term makes it 2-way (free).
// Read chunk ck = lm ^ (ln&3) ^ ((ln>>2)&3) (frag-row bases are multiples of 16).
// Race audit: barrier#1 (after vmcnt) = tile-t visibility; barrier#2 (after lgkm(0))
// = all waves' reads of buf done before next iter's restage of it. MFMAs register-only
// after barrier#2 (overlap other waves' staging).
template <int KD>
static __device__ __forceinline__ void gemm_core8(
    const __hip_bfloat16* __restrict__ Ar,  // 256 rows x KD (k-contiguous)
    const __hip_bfloat16* __restrict__ Br,  // 128 rows x KD
    __hip_bfloat16* As, __hip_bfloat16* Bs, f32x4 (&acc)[4][4]) {
  constexpr int NT = KD / 32;
  const int tid = threadIdx.x;
  const int lane = tid & 63, w = tid >> 6;   // w 0..7
  const int wm = w >> 1, wn = w & 1;
  const int ln = lane & 15, lm = lane >> 4;
  // staging: row (within 128-half) = w*16 + (lane>>2); slot = lane&3;
  // source chunk g = slot ^ perm(row) = (lane&3) ^ ((lane>>2)&3) ^ ((lane>>4)&3)
  const int srow = lane >> 2;
  const int schk = (lane & 3) ^ ((lane >> 2) & 3) ^ ((lane >> 4) & 3);
  const __hip_bfloat16* aS = Ar + (size_t)(w * 16 + srow) * KD + schk * 8;
  const __hip_bfloat16* bS = Br + (size_t)(w * 16 + srow) * KD + schk * 8;
  // read chunk (same for A and B frag rows; bases multiple of 16)
  const int ck = (lm ^ (ln & 3) ^ ((ln >> 2) & 3)) * 8;
  int ra[4], rb[4];
#pragma unroll
  for (int mf = 0; mf < 4; mf++) ra[mf] = (wm * 64 + mf * 16 + ln) * 32 + ck;
#pragma unroll
  for (int nf = 0; nf < 4; nf++) rb[nf] = (wn * 64 + nf * 16 + ln) * 32 + ck;

#define STGA(h, kt, buf) \
  stage16(aS + (size_t)((h) * 128) * KD + (kt) * 32, \
          As + (buf) * 8192 + ((h) * 128 + w * 16) * 32)
#define STGB(kt, buf) \
  stage16(bS + (size_t)(kt) * 32, Bs + (buf) * 4096 + (w * 16) * 32)

  // prologue: tile 0 -> buf 0
  STGA(0, 0, 0); STGA(1, 0, 0); STGB(0, 0);

  short8 af[4], bf[4];
  for (int t = 0; t < NT; t++) {
    const int buf = t & 1, nb = buf ^ 1;
    const bool has = (t + 1 < NT);
    const __hip_bfloat16* Ab = As + buf * 8192;
    const __hip_bfloat16* Bb = Bs + buf * 4096;
    if (has) { STGA(0, t + 1, nb); STGA(1, t + 1, nb); STGB(t + 1, nb); }
    if (has) asm volatile("s_waitcnt vmcnt(3)" ::: "memory");  // tile t landed
    else     asm volatile("s_waitcnt vmcnt(0)" ::: "memory");
    asm volatile("s_barrier" ::: "memory");  // tile t visible to all waves
#pragma unroll
    for (int mf = 0; mf < 4; mf++) af[mf] = *(const short8*)&Ab[ra[mf]];
#pragma unroll
    for (int nf = 0; nf < 4; nf++) bf[nf] = *(const short8*)&Bb[rb[nf]];
    asm volatile("s_waitcnt lgkmcnt(0)" ::: "memory");
    __builtin_amdgcn_sched_barrier(0);
    asm volatile("s_barrier" ::: "memory");  // all reads done -> restage safe
    __builtin_amdgcn_s_setprio(1);
#pragma unroll
    for (int nf = 0; nf < 4; nf++)
#pragma unroll
      for (int mf = 0; mf < 4; mf++)
        acc[mf][nf] = __builtin_amdgcn_mfma_f32_16x16x32_bf16(af[mf], bf[nf], acc[mf][nf], 0, 0, 0);
    __builtin_amdgcn_s_setprio(0);
  }
#undef STGA
#undef STGB
}

// ---------------- GEMM1 + fused 7-tap conv epilogue: writes dwT directly ----------------
// A-side = xbT n (256), B-side = w1b o (128). 392 blocks = 8 x 49, 512 thr.
__global__ __launch_bounds__(512, 4) void k_gemm1(const __hip_bfloat16* __restrict__ xbT,
                                                  const __hip_bfloat16* __restrict__ w1b,
                                                  const float* __restrict__ b1,
                                                  const float* __restrict__ weff,
                                                  const float* __restrict__ beff,
                                                  __hip_bfloat16* __restrict__ dwT) {
  __shared__ __hip_bfloat16 As[2 * 256 * 32];
  __shared__ __hip_bfloat16 Bs[2 * 128 * 32];
  int xcd = blockIdx.x & 7, i = blockIdx.x >> 3;
  int id = xcd * 49 + i;          // bijective (392 % 8 == 0); o-tile fastest
  int nt = id >> 2, ot = id & 3;
  int n0 = nt * 256, o0 = ot * 128;
  f32x4 acc[4][4];
#pragma unroll
  for (int a = 0; a < 4; a++)
#pragma unroll
    for (int c = 0; c < 4; c++) acc[a][c] = (f32x4){0.f, 0.f, 0.f, 0.f};
  gemm_core8<1024>(xbT + (size_t)n0 * CIN, w1b + (size_t)o0 * CIN, As, Bs, acc);

  int tid = threadIdx.x, lane = tid & 63, w = tid >> 6;
  int wm = w >> 1, wn = w & 1, ln = lane & 15, lm = lane >> 4;
  bool hiT = (lm & 1);
#pragma unroll
  for (int nf = 0; nf < 4; nf++) {
    int o = o0 + wn * 64 + nf * 16 + ln;
    float e[7];
#pragma unroll
    for (int u = 0; u < 7; u++) e[u] = weff[o * 8 + u];
    float be = beff[o];
    float bo = b1[o];
#pragma unroll
    for (int mf = 0; mf < 4; mf++) {
      float av[4], pv[4];
#pragma unroll
      for (int j = 0; j < 4; j++) av[j] = acc[mf][nf][j] + bo;
#pragma unroll
      for (int j = 0; j < 4; j++) pv[j] = __shfl_xor(av[j], 16, 64);
      float ov[4];
      if (hiT) {
#pragma unroll
        for (int j = 0; j < 4; j++) {
          float s = be;
#pragma unroll
          for (int u = 0; u < 7; u++) {
            int ss = 4 + j + u - 3;
            if (ss >= 0 && ss < 8) s += e[u] * (ss < 4 ? pv[ss] : av[ss - 4]);
          }
          ov[j] = s;
        }
      } else {
#pragma unroll
        for (int j = 0; j < 4; j++) {
          float s = be;
#pragma unroll
          for (int u = 0; u < 7; u++) {
            int ss = j + u - 3;
            if (ss >= 0 && ss < 8) s += e[u] * (ss < 4 ? av[ss] : pv[ss - 4]);
          }
          ov[j] = s;
        }
      }
      // row = n0 + wm*64 + mf*16 + lm*4 + j; group start (mult of 8):
      int grow = n0 + wm * 64 + mf * 16 + ((lm >> 1) & 1) * 8;
      int gidx = grow >> 3;  // = b*196 + hw
      int gb = gidx / HWS, ghw = gidx - gb * HWS;
      int tb = hiT ? 4 : 0;
#pragma unroll
      for (int j = 0; j < 4; j++) {
        size_t rr = (size_t)gb * NPB + (size_t)(tb + j) * HWS + ghw;
        dwT[rr * ICH + o] = __float2bfloat16(ov[j]);
      }
    }
  }
}

// ---------------- GEMM2: out = w2b . dwT + b2 + residual; bounced float4 epilogue ----------------
// A-side = w2b m (256), B-side = dwT n (128). 784 blocks = 8 x 98, 512 thr.
__global__ __launch_bounds__(512, 4) void k_gemm2(const __hip_bfloat16* __restrict__ dwT,
                                                  const __hip_bfloat16* __restrict__ w2b,
                                                  const float* __restrict__ b2,
                                                  const float* __restrict__ xres,
                                                  float* __restrict__ out) {
  __shared__ __align__(16) char smem[49152];
  __hip_bfloat16* As = (__hip_bfloat16*)smem;            // 2*256*32 = 32768 B
  __hip_bfloat16* Bs = (__hip_bfloat16*)(smem + 32768);  // 2*128*32 = 16384 B
  int xcd = blockIdx.x & 7, i = blockIdx.x >> 3;
  int id = xcd * 98 + i;          // bijective (784 % 8 == 0); m-tile fastest
  int nt = id >> 2, mt = id & 3;
  int n0 = nt * 128, m0 = mt * 256;
  f32x4 acc[4][4];
#pragma unroll
  for (int a = 0; a < 4; a++)
#pragma unroll
    for (int c = 0; c < 4; c++) acc[a][c] = (f32x4){0.f, 0.f, 0.f, 0.f};
  gemm_core8<512>(w2b + (size_t)m0 * ICH, dwT + (size_t)n0 * ICH, As, Bs, acc);

  int tid = threadIdx.x, lane = tid & 63, w = tid >> 6;
  int wm = w >> 1, wn = w & 1, ln = lane & 15, lm = lane >> 4;
  float* arr = (float*)smem;  // bounce: [64 o2-rows][132 cols] fp32 per pass (33792 B)
  int fc = tid & 31, fr = tid >> 5;  // fr 0..15, wave-uniform
  int n2 = n0 + fc * 4;
  int bb = n2 / NPB, r = n2 - bb * NPB;
  int t2 = r / HWS, hw = r - t2 * HWS;   // n2 mult of 4 -> hw mult of 4 <= 192: float4 safe
  size_t base4 = ((size_t)((bb * TT + t2) * CIN)) * HWS + hw;
#pragma unroll
  for (int p = 0; p < 4; p++) {
    __syncthreads();
    // o2 row = m0 + wm*64 + mf*16 + lm*4 + j; pass p covers wm == p
    if (wm == p) {
#pragma unroll
      for (int nf = 0; nf < 4; nf++)
#pragma unroll
        for (int mf = 0; mf < 4; mf++)
#pragma unroll
          for (int j = 0; j < 4; j++)
            arr[(mf * 16 + lm * 4 + j) * 132 + wn * 64 + nf * 16 + ln] = acc[mf][nf][j];
    }
    __syncthreads();
#pragma unroll
    for (int it = 0; it < 4; it++) {
      int o2l = it * 16 + fr;
      f32x4 v = *(const f32x4*)&arr[o2l * 132 + fc * 4];
      int o2 = m0 + p * 64 + o2l;
      float bo = b2[o2];
      size_t a = base4 + (size_t)o2 * HWS;
      float4 xr = *(const float4*)(xres + a);
      float4 ov = make_float4(v[0] + bo + xr.x, v[1] + bo + xr.y,
                              v[2] + bo + xr.z, v[3] + bo + xr.w);
      *(float4*)(out + a) = ov;
    }
  }
}

extern "C" void kernel_launch(void* const* d_in, const int* in_sizes, int n_in,
                              void* d_out, int out_size, void* d_ws, size_t ws_size,
                              hipStream_t stream) {
  const float* x   = (const float*)d_in[0];
  const float* w1  = (const float*)d_in[1];
  const float* b1  = (const float*)d_in[2];
  const float* wb1 = (const float*)d_in[3];
  const float* bb1 = (const float*)d_in[4];
  const float* wb2 = (const float*)d_in[5];
  const float* bb2 = (const float*)d_in[6];
  const float* wb3 = (const float*)d_in[7];
  const float* bb3 = (const float*)d_in[8];
  const float* wb4 = (const float*)d_in[9];
  const float* bb4 = (const float*)d_in[10];
  const float* w2  = (const float*)d_in[11];
  const float* b2  = (const float*)d_in[12];
  float* out = (float*)d_out;

  // d_out as scratch: xbT bf16 [NF][CIN] at offset 0 (51.4MB; dead before gemm2 writes out)
  __hip_bfloat16* xbT = (__hip_bfloat16*)d_out;

  // ws: dwT 25.69MB + w1b 1MB + w2b 1MB + weff 16KB + beff 2KB
  char* ws = (char*)d_ws;
  __hip_bfloat16* dwT = (__hip_bfloat16*)ws;
  __hip_bfloat16* w1b = (__hip_bfloat16*)(ws + 25690112);
  __hip_bfloat16* w2b = (__hip_bfloat16*)(ws + 25690112 + 1048576);
  float* weff = (float*)(ws + 25690112 + 2097152);
  float* beff = weff + 4096;

  k_prep_w<<<(CIN * ICH + 255) / 256, 256, 0, stream>>>(
      w1, w2, wb1, bb1, wb2, bb2, wb3, bb3, wb4, bb4, w1b, w2b, weff, beff);
  k_prep_x<<<1024, 448, 0, stream>>>(x, xbT);
  k_gemm1<<<392, 512, 0, stream>>>(xbT, w1b, b1, weff, beff, dwT);
  k_gemm2<<<784, 512, 0, stream>>>(dwT, w2b, b2, x, out);
}

// Round 16
// 117.378 us; speedup vs baseline: 1.0633x; 1.0633x over previous
//
#include <hip/hip_runtime.h>
#include <hip/hip_bf16.h>

typedef short short8 __attribute__((ext_vector_type(8)));
typedef float f32x4 __attribute__((ext_vector_type(4)));
typedef unsigned int uint;

#define CB   16
#define TT   8
#define CIN  1024
#define ICH  512
#define HWS  196
#define NPB  1568   // cols per batch (196*8)
#define NF   25088  // flat cols = 16*1568

static __device__ __forceinline__ unsigned short f2bf(float f) {
  __hip_bfloat16 h = __float2bfloat16(f); unsigned short u; __builtin_memcpy(&u, &h, 2); return u;
}

// async global->LDS, 16B per lane; LDS dest is wave-uniform base + lane*16
static __device__ __forceinline__ void stage16(const void* g, void* l) {
  __builtin_amdgcn_global_load_lds(
      (const __attribute__((address_space(1))) unsigned int*)(unsigned long long)g,
      (__attribute__((address_space(3))) unsigned int*)(unsigned int)(unsigned long long)l,
      16, 0, 0);
}

// ---------------- weight prep (vectorized: 4 elems/thread, 512 blocks) ----------------
__global__ void k_prep_w(const float* __restrict__ w1, const float* __restrict__ w2,
    const float* __restrict__ wb1, const float* __restrict__ bb1,
    const float* __restrict__ wb2, const float* __restrict__ bb2,
    const float* __restrict__ wb3, const float* __restrict__ bb3,
    const float* __restrict__ wb4, const float* __restrict__ bb4,
    __hip_bfloat16* __restrict__ w1b, __hip_bfloat16* __restrict__ w2b,
    float* __restrict__ weff, float* __restrict__ beff) {
  int g = blockIdx.x * 256 + threadIdx.x;   // 0..131071 (512 blocks)
  int idx4 = g * 4;
  if (idx4 < CIN * ICH) {
    float4 a = *(const float4*)(w1 + idx4);
    ushort4 pa = {f2bf(a.x), f2bf(a.y), f2bf(a.z), f2bf(a.w)};
    *(ushort4*)((unsigned short*)w1b + idx4) = pa;
    float4 b = *(const float4*)(w2 + idx4);
    ushort4 pb = {f2bf(b.x), f2bf(b.y), f2bf(b.z), f2bf(b.w)};
    *(ushort4*)((unsigned short*)w2b + idx4) = pb;
  }
  if (g < ICH) {
    float e[7];
#pragma unroll
    for (int u = 0; u < 7; u++) e[u] = wb4[g * 7 + u];
#pragma unroll
    for (int u = 0; u < 5; u++) e[u + 1] += wb3[g * 5 + u];
#pragma unroll
    for (int u = 0; u < 3; u++) e[u + 2] += wb2[g * 3 + u];
    e[3] += wb1[g];
#pragma unroll
    for (int u = 0; u < 7; u++) weff[g * 8 + u] = e[u];
    weff[g * 8 + 7] = 0.f;
    beff[g] = bb1[g] + bb2[g] + bb3[g] + bb4[g];
  }
}

// ---------------- x transpose v3 (R14-proven) ----------------
__global__ __launch_bounds__(448) void k_prep_x(const float* __restrict__ x,
                                                __hip_bfloat16* __restrict__ xbT) {
  __shared__ unsigned short tile[196 * 128];  // 50176 B
  int xcd = blockIdx.x & 7, i = blockIdx.x >> 3;
  int id = xcd * 128 + i;
  int bt = id >> 3, cr = id & 7;
  int c0 = cr * 128;
  int b = bt >> 3, t = bt & 7;
  const float* src = x + ((size_t)bt * CIN + c0) * HWS;
  int tid = threadIdx.x;
#pragma unroll
  for (int it = 0; it < 14; it++) {
    int idx = it * 448 + tid;               // = c*49 + hwq
    f32x4 v = *(const f32x4*)(src + (size_t)idx * 4);
    int c = idx / 49, hwq = idx - c * 49;
#pragma unroll
    for (int j = 0; j < 4; j++) {
      int hw = hwq * 4 + j;
      int slot = (c >> 3) ^ ((hw + (hw >> 2)) & 15);
      tile[hw * 128 + slot * 8 + (c & 7)] = f2bf(v[j]);
    }
  }
  __syncthreads();
  __hip_bfloat16* dstb = xbT + ((size_t)b * NPB + (size_t)t) * CIN + c0;
#pragma unroll
  for (int it = 0; it < 7; it++) {
    int idx = it * 448 + tid;               // = hw*16 + co
    int hw = idx >> 4, co = idx & 15;
    int slot = co ^ ((hw + (hw >> 2)) & 15);
    uint4 val = *(const uint4*)&tile[hw * 128 + slot * 8];
    *(uint4*)(dstb + (size_t)(hw * 8) * CIN + co * 8) = val;
  }
}

// ---------------- 256x256 GEMM core, BK=64, 16 waves (4x4), 64x64 per wave ----------------
// (R12/R14-proven best)
template <int KD>
static __device__ __forceinline__ void gemm_core16(
    const __hip_bfloat16* __restrict__ Ar,  // 256 rows x KD (k-contiguous)
    const __hip_bfloat16* __restrict__ Br,  // 256 rows x KD
    __hip_bfloat16* As, __hip_bfloat16* Bs, f32x4 (&acc)[4][4]) {
  constexpr int NT = KD / 64;
  const int tid = threadIdx.x;
  const int lane = tid & 63, w = tid >> 6;   // w 0..15
  const int wm = w >> 2, wn = w & 3;
  const int ln = lane & 15, lm = lane >> 4;
  const int srow = lane >> 3;                 // 0..7 (== row&7)
  const int schk = (lane & 7) ^ srow;
  const __hip_bfloat16* aS = Ar + (size_t)(w * 8 + srow) * KD + schk * 8;
  const __hip_bfloat16* bS = Br + (size_t)(w * 8 + srow) * KD + schk * 8;
  __hip_bfloat16* aD = As + (w * 8) * 64;
  __hip_bfloat16* bD = Bs + (w * 8) * 64;
  const int ck0 = ((lm) ^ (ln & 7)) * 8;
  const int ck1 = ((4 + lm) ^ (ln & 7)) * 8;
  const int rab = (wm * 16 + ln) * 64;  // + mf*4096
  const int rbb = (wn * 64 + ln) * 64;  // + nf*1024

#define STG(src, dst, h, kt, buf) \
  stage16(src + (size_t)((h) * 128) * KD + (kt) * 64, dst + (buf) * 16384 + ((h) * 128) * 64)

  STG(bS, bD, 0, 0, 0); STG(bS, bD, 1, 0, 0);
  STG(aS, aD, 0, 0, 0); STG(aS, aD, 1, 0, 0);

  short8 af0, af1, bfA[4], bfB[4];
  for (int t = 0; t < NT; t++) {
    const int buf = t & 1, nb = buf ^ 1;
    const bool has = (t + 1 < NT);
    const __hip_bfloat16* Ab = As + buf * 16384;
    const __hip_bfloat16* Bb = Bs + buf * 16384;
    // ---- p0: mf0,1 x ck0 ----
    if (has) STG(bS, bD, 0, t + 1, nb);
    if (has) asm volatile("s_waitcnt vmcnt(2)" ::: "memory");
    else     asm volatile("s_waitcnt vmcnt(1)" ::: "memory");
    asm volatile("s_barrier" ::: "memory");
    af0 = *(const short8*)&Ab[rab + ck0];
    af1 = *(const short8*)&Ab[rab + 4096 + ck0];
#pragma unroll
    for (int nf = 0; nf < 4; nf++) bfA[nf] = *(const short8*)&Bb[rbb + nf * 1024 + ck0];
    asm volatile("s_waitcnt lgkmcnt(0)" ::: "memory");
    __builtin_amdgcn_sched_barrier(0);
    __builtin_amdgcn_s_setprio(1);
#pragma unroll
    for (int nf = 0; nf < 4; nf++) {
      acc[0][nf] = __builtin_amdgcn_mfma_f32_16x16x32_bf16(af0, bfA[nf], acc[0][nf], 0, 0, 0);
      acc[1][nf] = __builtin_amdgcn_mfma_f32_16x16x32_bf16(af1, bfA[nf], acc[1][nf], 0, 0, 0);
    }
    __builtin_amdgcn_s_setprio(0);
    // ---- p1: mf0,1 x ck1 ----
    if (has) STG(bS, bD, 1, t + 1, nb);
    af0 = *(const short8*)&Ab[rab + ck1];
    af1 = *(const short8*)&Ab[rab + 4096 + ck1];
#pragma unroll
    for (int nf = 0; nf < 4; nf++) bfB[nf] = *(const short8*)&Bb[rbb + nf * 1024 + ck1];
    asm volatile("s_waitcnt lgkmcnt(0)" ::: "memory");
    __builtin_amdgcn_sched_barrier(0);
    __builtin_amdgcn_s_setprio(1);
#pragma unroll
    for (int nf = 0; nf < 4; nf++) {
      acc[0][nf] = __builtin_amdgcn_mfma_f32_16x16x32_bf16(af0, bfB[nf], acc[0][nf], 0, 0, 0);
      acc[1][nf] = __builtin_amdgcn_mfma_f32_16x16x32_bf16(af1, bfB[nf], acc[1][nf], 0, 0, 0);
    }
    __builtin_amdgcn_s_setprio(0);
    // ---- p2: mf2,3 x ck0 ----
    if (has) STG(aS, aD, 0, t + 1, nb);
    if (has) asm volatile("s_waitcnt vmcnt(3)" ::: "memory");
    else     asm volatile("s_waitcnt vmcnt(0)" ::: "memory");
    asm volatile("s_barrier" ::: "memory");
    af0 = *(const short8*)&Ab[rab + 2 * 4096 + ck0];
    af1 = *(const short8*)&Ab[rab + 3 * 4096 + ck0];
    asm volatile("s_waitcnt lgkmcnt(0)" ::: "memory");
    __builtin_amdgcn_sched_barrier(0);
    __builtin_amdgcn_s_setprio(1);
#pragma unroll
    for (int nf = 0; nf < 4; nf++) {
      acc[2][nf] = __builtin_amdgcn_mfma_f32_16x16x32_bf16(af0, bfA[nf], acc[2][nf], 0, 0, 0);
      acc[3][nf] = __builtin_amdgcn_mfma_f32_16x16x32_bf16(af1, bfA[nf], acc[3][nf], 0, 0, 0);
    }
    __builtin_amdgcn_s_setprio(0);
    // ---- p3: mf2,3 x ck1; end barrier before MFMAs ----
    if (has) STG(aS, aD, 1, t + 1, nb);
    af0 = *(const short8*)&Ab[rab + 2 * 4096 + ck1];
    af1 = *(const short8*)&Ab[rab + 3 * 4096 + ck1];
    asm volatile("s_waitcnt lgkmcnt(0)" ::: "memory");
    __builtin_amdgcn_sched_barrier(0);
    asm volatile("s_barrier" ::: "memory");
    __builtin_amdgcn_s_setprio(1);
#pragma unroll
    for (int nf = 0; nf < 4; nf++) {
      acc[2][nf] = __builtin_amdgcn_mfma_f32_16x16x32_bf16(af0, bfB[nf], acc[2][nf], 0, 0, 0);
      acc[3][nf] = __builtin_amdgcn_mfma_f32_16x16x32_bf16(af1, bfB[nf], acc[3][nf], 0, 0, 0);
    }
    __builtin_amdgcn_s_setprio(0);
  }
#undef STG
}

// ---------------- GEMM1 + fused 7-tap conv epilogue: writes dwT directly ----------------
__global__ __launch_bounds__(1024, 4) void k_gemm1(const __hip_bfloat16* __restrict__ xbT,
                                                   const __hip_bfloat16* __restrict__ w1b,
                                                   const float* __restrict__ b1,
                                                   const float* __restrict__ weff,
                                                   const float* __restrict__ beff,
                                                   __hip_bfloat16* __restrict__ dwT) {
  __shared__ __hip_bfloat16 As[2 * 256 * 64];
  __shared__ __hip_bfloat16 Bs[2 * 256 * 64];
  int xcd = blockIdx.x & 7, i = blockIdx.x >> 3;
  int id = (xcd < 4 ? xcd * 25 : 100 + (xcd - 4) * 24) + i;
  int rt = id >> 1, ot = id & 1;
  int n0 = rt * 256, o0 = ot * 256;
  f32x4 acc[4][4];
#pragma unroll
  for (int a = 0; a < 4; a++)
#pragma unroll
    for (int c = 0; c < 4; c++) acc[a][c] = (f32x4){0.f, 0.f, 0.f, 0.f};
  gemm_core16<1024>(xbT + (size_t)n0 * CIN, w1b + (size_t)o0 * CIN, As, Bs, acc);

  int tid = threadIdx.x, lane = tid & 63, w = tid >> 6;
  int wm = w >> 2, wn = w & 3, ln = lane & 15, lm = lane >> 4;
  bool hiT = (lm & 1);
#pragma unroll
  for (int nf = 0; nf < 4; nf++) {
    int o = o0 + wn * 64 + nf * 16 + ln;
    float e[7];
#pragma unroll
    for (int u = 0; u < 7; u++) e[u] = weff[o * 8 + u];
    float be = beff[o];
    float bo = b1[o];
#pragma unroll
    for (int mf = 0; mf < 4; mf++) {
      float av[4], pv[4];
#pragma unroll
      for (int j = 0; j < 4; j++) av[j] = acc[mf][nf][j] + bo;
#pragma unroll
      for (int j = 0; j < 4; j++) pv[j] = __shfl_xor(av[j], 16, 64);
      float ov[4];
      if (hiT) {
#pragma unroll
        for (int j = 0; j < 4; j++) {
          float s = be;
#pragma unroll
          for (int u = 0; u < 7; u++) {
            int ss = 4 + j + u - 3;
            if (ss >= 0 && ss < 8) s += e[u] * (ss < 4 ? pv[ss] : av[ss - 4]);
          }
          ov[j] = s;
        }
      } else {
#pragma unroll
        for (int j = 0; j < 4; j++) {
          float s = be;
#pragma unroll
          for (int u = 0; u < 7; u++) {
            int ss = j + u - 3;
            if (ss >= 0 && ss < 8) s += e[u] * (ss < 4 ? av[ss] : pv[ss - 4]);
          }
          ov[j] = s;
        }
      }
      int grow = n0 + mf * 64 + wm * 16 + ((lm >> 1) & 1) * 8;
      int gidx = grow >> 3;  // = b*196 + hw
      int gb = gidx / HWS, ghw = gidx - gb * HWS;
      int tb = hiT ? 4 : 0;
#pragma unroll
      for (int j = 0; j < 4; j++) {
        size_t rr = (size_t)gb * NPB + (size_t)(tb + j) * HWS + ghw;
        dwT[rr * ICH + o] = __float2bfloat16(ov[j]);
      }
    }
  }
}

// ---------------- GEMM2: out = w2b . dwT + b2 + residual; bounced float4 epilogue ----------------
__global__ __launch_bounds__(1024, 4) void k_gemm2(const __hip_bfloat16* __restrict__ dwT,
                                                   const __hip_bfloat16* __restrict__ w2b,
                                                   const float* __restrict__ b2,
                                                   const float* __restrict__ xres,
                                                   float* __restrict__ out) {
  __shared__ __align__(16) char smem[131072];
  __hip_bfloat16* As = (__hip_bfloat16*)smem;
  __hip_bfloat16* Bs = (__hip_bfloat16*)(smem + 65536);
  int id = (blockIdx.x & 7) * 49 + (blockIdx.x >> 3);
  int nt = id >> 2, mt = id & 3;
  int n0 = nt * 256, m0 = mt * 256;
  f32x4 acc[4][4];
#pragma unroll
  for (int a = 0; a < 4; a++)
#pragma unroll
    for (int c = 0; c < 4; c++) acc[a][c] = (f32x4){0.f, 0.f, 0.f, 0.f};
  gemm_core16<512>(w2b + (size_t)m0 * ICH, dwT + (size_t)n0 * ICH, As, Bs, acc);

  int tid = threadIdx.x, lane = tid & 63, w = tid >> 6;
  int wm = w >> 2, wn = w & 3, ln = lane & 15, lm = lane >> 4;
  float* arr = (float*)smem;  // bounce: [64 o2-rows][260 cols] fp32 per pass
  int fc = tid & 63, fr = tid >> 6;  // fr 0..15, wave-uniform
  int n2 = n0 + fc * 4;
  int bb = n2 / NPB, r = n2 - bb * NPB;
  int t2 = r / HWS, hw = r - t2 * HWS;
  size_t base4 = ((size_t)((bb * TT + t2) * CIN)) * HWS + hw;
#pragma unroll
  for (int p = 0; p < 4; p++) {
    __syncthreads();
#pragma unroll
    for (int nf = 0; nf < 4; nf++)
#pragma unroll
      for (int j = 0; j < 4; j++)
        arr[(wm * 16 + lm * 4 + j) * 260 + wn * 64 + nf * 16 + ln] = acc[p][nf][j];
    __syncthreads();
#pragma unroll
    for (int it = 0; it < 4; it++) {
      int o2l = it * 16 + fr;
      f32x4 v = *(const f32x4*)&arr[o2l * 260 + fc * 4];
      int o2 = m0 + p * 64 + o2l;
      float bo = b2[o2];
      size_t a = base4 + (size_t)o2 * HWS;
      float4 xr = *(const float4*)(xres + a);
      float4 ov = make_float4(v[0] + bo + xr.x, v[1] + bo + xr.y,
                              v[2] + bo + xr.z, v[3] + bo + xr.w);
      *(float4*)(out + a) = ov;
    }
  }
}

extern "C" void kernel_launch(void* const* d_in, const int* in_sizes, int n_in,
                              void* d_out, int out_size, void* d_ws, size_t ws_size,
                              hipStream_t stream) {
  const float* x   = (const float*)d_in[0];
  const float* w1  = (const float*)d_in[1];
  const float* b1  = (const float*)d_in[2];
  const float* wb1 = (const float*)d_in[3];
  const float* bb1 = (const float*)d_in[4];
  const float* wb2 = (const float*)d_in[5];
  const float* bb2 = (const float*)d_in[6];
  const float* wb3 = (const float*)d_in[7];
  const float* bb3 = (const float*)d_in[8];
  const float* wb4 = (const float*)d_in[9];
  const float* bb4 = (const float*)d_in[10];
  const float* w2  = (const float*)d_in[11];
  const float* b2  = (const float*)d_in[12];
  float* out = (float*)d_out;

  // d_out as scratch: xbT bf16 [NF][CIN] at offset 0 (51.4MB; dead before gemm2 writes out)
  __hip_bfloat16* xbT = (__hip_bfloat16*)d_out;

  // ws: dwT 25.69MB + w1b 1MB + w2b 1MB + weff 16KB + beff 2KB
  char* ws = (char*)d_ws;
  __hip_bfloat16* dwT = (__hip_bfloat16*)ws;
  __hip_bfloat16* w1b = (__hip_bfloat16*)(ws + 25690112);
  __hip_bfloat16* w2b = (__hip_bfloat16*)(ws + 25690112 + 1048576);
  float* weff = (float*)(ws + 25690112 + 2097152);
  float* beff = weff + 4096;

  k_prep_w<<<512, 256, 0, stream>>>(
      w1, w2, wb1, bb1, wb2, bb2, wb3, bb3, wb4, bb4, w1b, w2b, weff, beff);
  k_prep_x<<<1024, 448, 0, stream>>>(x, xbT);
  k_gemm1<<<196, 1024, 0, stream>>>(xbT, w1b, b1, weff, beff, dwT);
  k_gemm2<<<392, 1024, 0, stream>>>(dwT, w2b, b2, x, out);
}